// Round 1
// baseline (370.366 us; speedup 1.0000x reference)
//
#include <hip/hip_runtime.h>
#include <math.h>

typedef __bf16 bf16x8 __attribute__((ext_vector_type(8)));
typedef float f32x4 __attribute__((ext_vector_type(4)));
typedef unsigned short u16;

#define LD 72  // LDS row stride in ushorts: multiple of 8 (16B-aligned b128 rows), dword-stride 36 % 32 = 4 -> good bank spread

__device__ __forceinline__ u16 f2b(float f) {
  // fp32 -> bf16 round-to-nearest-even (finite inputs only)
  unsigned u = __builtin_bit_cast(unsigned, f);
  u = (u + 0x7fffu + ((u >> 16) & 1u)) >> 16;
  return (u16)u;
}

__device__ __forceinline__ f32x4 mfma16(bf16x8 a, bf16x8 b, f32x4 c) {
  return __builtin_amdgcn_mfma_f32_16x16x32_bf16(a, b, c, 0, 0, 0);
}

// Prep: M_t[c'][c] = scale * sum_h Wq[c][h]*Wk[c'][h]  (i.e. (scale*Wq@Wk^T)^T, transposed+padded for B-fragment reads)
//       Wv_t[h][c] = Wv[c][h]
// Both bf16, row stride LD, cols [48,LD) zeroed. Written to ws.
__global__ __launch_bounds__(256) void head_prep(const float* __restrict__ Wq,
                                                 const float* __restrict__ Wk,
                                                 const float* __restrict__ Wv,
                                                 u16* __restrict__ ws) {
  const float scale = 0.14433756729740643f;  // 1/sqrt(48)
  for (int idx = threadIdx.x; idx < 48 * LD; idx += 256) {
    int r = idx / LD;  // c' for Mt, h for Wv_t
    int c = idx % LD;
    float mv = 0.f, wv = 0.f;
    if (c < 48) {
      float acc = 0.f;
      for (int h = 0; h < 48; ++h) acc += Wq[c * 48 + h] * Wk[r * 48 + h];
      mv = acc * scale;
      wv = Wv[c * 48 + r];
    }
    ws[idx] = f2b(mv);
    ws[48 * LD + idx] = f2b(wv);
  }
}

// One workgroup (4 waves) per batch element. Wave w owns t-rows [16w,16w+16).
// qm = x @ M ; S = qm @ x^T (== scale*q@k^T) ; P = softmax_causal(S) ; out = P @ (x@Wv)
__global__ __launch_bounds__(256, 4) void head_main(const float* __restrict__ x,
                                                    const u16* __restrict__ wimg,
                                                    float* __restrict__ out) {
  __shared__ u16 lds[272 * LD];            // 19584 u16 = 38.25 KB -> 4 blocks/CU
  u16* const W_M = lds;                    // Mt  [48][LD]
  u16* const W_V = lds + 48 * LD;          // Wv_t[48][LD]
  u16* const X   = lds + 96 * LD;          // X   [64][LD] bf16 (c padded); overlaid by P after S
  u16* const QM  = lds + 160 * LD;         // QM  [64][LD] (c' padded)
  u16* const VT  = lds + 224 * LD;         // V_t [48][LD] (h-major, s inner)

  const int tid  = threadIdx.x;
  const int lane = tid & 63;
  const int w    = tid >> 6;               // wave id = t-tile
  const int qd   = lane >> 4;
  const int col  = lane & 15;
  const long b   = blockIdx.x;

  // ---- stage weights image (ws -> LDS, already bf16 + padded) ----
  {
    const uint4* src = (const uint4*)wimg;
    uint4* dst = (uint4*)lds;
    #pragma unroll
    for (int i = 0; i < 4; ++i) {
      int idx = tid + i * 256;
      if (idx < (96 * LD * 2) / 16) dst[idx] = src[idx];
    }
  }
  // ---- stage x -> bf16 LDS (coalesced float4 global reads) ----
  {
    const float* xb = x + b * 3072;
    #pragma unroll
    for (int it = 0; it < 3; ++it) {
      int flat = tid * 4 + it * 1024;      // 3072 floats, fully coalesced
      float4 v = *(const float4*)(xb + flat);
      int row = flat / 48;
      int c0  = flat % 48;                 // multiple of 4
      ushort4 pk;
      pk.x = f2b(v.x); pk.y = f2b(v.y); pk.z = f2b(v.z); pk.w = f2b(v.w);
      *(ushort4*)(X + row * LD + c0) = pk;
    }
    // zero pad cols [48,72) of X and QM (K-tile 1 reads c in [32,64))
    int zr = tid >> 2;
    int zc = 48 + (tid & 3) * 6;
    #pragma unroll
    for (int j = 0; j < 6; ++j) {
      X[zr * LD + zc + j] = 0;
      QM[zr * LD + zc + j] = 0;
    }
  }
  __syncthreads();

  // ---- projections: V = x@Wv -> VT (transposed), QM = x@M -> QM ----
  {
    const int arow = (16 * w + col) * LD + qd * 8;
    bf16x8 xa0 = *(const bf16x8*)(X + arow);
    bf16x8 xa1 = *(const bf16x8*)(X + arow + 32);
    #pragma unroll
    for (int n = 0; n < 3; ++n) {
      const int brow = (16 * n + col) * LD + qd * 8;
      f32x4 av = {0.f, 0.f, 0.f, 0.f};
      f32x4 aq = {0.f, 0.f, 0.f, 0.f};
      av = mfma16(xa0, *(const bf16x8*)(W_V + brow), av);
      av = mfma16(xa1, *(const bf16x8*)(W_V + brow + 32), av);
      aq = mfma16(xa0, *(const bf16x8*)(W_M + brow), aq);
      aq = mfma16(xa1, *(const bf16x8*)(W_M + brow + 32), aq);
      // V tile: D[row=s_loc][col=h_loc]; write transposed VT[h][s], 4 consec s -> b64
      ushort4 pv;
      pv.x = f2b(av[0]); pv.y = f2b(av[1]); pv.z = f2b(av[2]); pv.w = f2b(av[3]);
      *(ushort4*)(VT + (16 * n + col) * LD + 16 * w + qd * 4) = pv;
      // QM tile: write natural [t][c'] (scalar b16 x4, cheap)
      #pragma unroll
      for (int i = 0; i < 4; ++i)
        QM[(16 * w + qd * 4 + i) * LD + 16 * n + col] = f2b(aq[i]);
    }
  }
  __syncthreads();

  // ---- S = QM @ X^T : A-frag from QM rows, B-frag from X rows (B[c'][s] = X[s][c']) ----
  float sv[4][4];  // [stile][reg]
  {
    const int arow = (16 * w + col) * LD + qd * 8;
    bf16x8 qa0 = *(const bf16x8*)(QM + arow);
    bf16x8 qa1 = *(const bf16x8*)(QM + arow + 32);
    #pragma unroll
    for (int st = 0; st < 4; ++st) {   // fixed trip: st>w is fully causal-masked later
      const int brow = (16 * st + col) * LD + qd * 8;
      f32x4 a = {0.f, 0.f, 0.f, 0.f};
      a = mfma16(qa0, *(const bf16x8*)(X + brow), a);
      a = mfma16(qa1, *(const bf16x8*)(X + brow + 32), a);
      #pragma unroll
      for (int i = 0; i < 4; ++i) sv[st][i] = a[i];
    }
  }

  // ---- causal mask + online-free softmax (T fits in regs) ----
  float m4[4] = {-INFINITY, -INFINITY, -INFINITY, -INFINITY};
  #pragma unroll
  for (int st = 0; st < 4; ++st) {
    #pragma unroll
    for (int i = 0; i < 4; ++i) {
      int tg = 16 * w + qd * 4 + i;
      int sg = 16 * st + col;
      float v = (sg <= tg) ? sv[st][i] : -INFINITY;
      sv[st][i] = v;
      m4[i] = fmaxf(m4[i], v);
    }
  }
  #pragma unroll
  for (int d = 1; d < 16; d <<= 1) {
    #pragma unroll
    for (int i = 0; i < 4; ++i) m4[i] = fmaxf(m4[i], __shfl_xor(m4[i], d, 64));
  }
  float l4[4] = {0.f, 0.f, 0.f, 0.f};
  #pragma unroll
  for (int st = 0; st < 4; ++st) {
    #pragma unroll
    for (int i = 0; i < 4; ++i) {
      float p = __expf(sv[st][i] - m4[i]);  // exp(-inf)=0 for masked
      sv[st][i] = p;
      l4[i] += p;
    }
  }
  #pragma unroll
  for (int d = 1; d < 16; d <<= 1) {
    #pragma unroll
    for (int i = 0; i < 4; ++i) l4[i] += __shfl_xor(l4[i], d, 64);
  }

  __syncthreads();  // all waves' S-MFMA reads of X are done; X region becomes P

  // ---- write P' (unnormalized probs) bf16; every (t,s) is written (zeros where masked) ----
  u16* const Pw = X + w * 16 * LD;  // per-wave 16x64 tile, stride LD
  #pragma unroll
  for (int st = 0; st < 4; ++st) {
    #pragma unroll
    for (int i = 0; i < 4; ++i)
      Pw[(qd * 4 + i) * LD + 16 * st + col] = f2b(sv[st][i]);
  }

  // ---- O = P' @ V (A from Pw, B from VT), then scale rows by 1/l ----
  f32x4 o0 = {0.f, 0.f, 0.f, 0.f}, o1 = o0, o2 = o0;
  #pragma unroll
  for (int kt = 0; kt < 2; ++kt) {
    bf16x8 pa = *(const bf16x8*)(Pw + col * LD + qd * 8 + 32 * kt);
    o0 = mfma16(pa, *(const bf16x8*)(VT + (0  + col) * LD + qd * 8 + 32 * kt), o0);
    o1 = mfma16(pa, *(const bf16x8*)(VT + (16 + col) * LD + qd * 8 + 32 * kt), o1);
    o2 = mfma16(pa, *(const bf16x8*)(VT + (32 + col) * LD + qd * 8 + 32 * kt), o2);
  }
  float rl[4];
  #pragma unroll
  for (int i = 0; i < 4; ++i) rl[i] = __builtin_amdgcn_rcpf(l4[i]);

  float* ob = out + b * 3072 + (16 * w + qd * 4) * 48 + col;
  #pragma unroll
  for (int i = 0; i < 4; ++i) {  // 64B-aligned 64B segments per quad -> fine store coalescing
    ob[i * 48 +  0] = o0[i] * rl[i];
    ob[i * 48 + 16] = o1[i] * rl[i];
    ob[i * 48 + 32] = o2[i] * rl[i];
  }
}

extern "C" void kernel_launch(void* const* d_in, const int* in_sizes, int n_in,
                              void* d_out, int out_size, void* d_ws, size_t ws_size,
                              hipStream_t stream) {
  const float* x  = (const float*)d_in[0];
  const float* Wq = (const float*)d_in[1];
  const float* Wk = (const float*)d_in[2];
  const float* Wv = (const float*)d_in[3];
  u16* wimg = (u16*)d_ws;  // 2 * 48*LD u16 = 13824 B
  head_prep<<<1, 256, 0, stream>>>(Wq, Wk, Wv, wimg);
  head_main<<<16384, 256, 0, stream>>>(x, wimg, (float*)d_out);
}

// Round 2
// 340.579 us; speedup vs baseline: 1.0875x; 1.0875x over previous
//
#include <hip/hip_runtime.h>
#include <math.h>

typedef __bf16 bf16x8 __attribute__((ext_vector_type(8)));
typedef float f32x4 __attribute__((ext_vector_type(4)));
typedef unsigned short u16;

__device__ __forceinline__ u16 f2b(float f) {
  // fp32 -> bf16 round-to-nearest-even (finite inputs only)
  unsigned u = __builtin_bit_cast(unsigned, f);
  u = (u + 0x7fffu + ((u >> 16) & 1u)) >> 16;
  return (u16)u;
}

__device__ __forceinline__ f32x4 mfma16(bf16x8 a, bf16x8 b, f32x4 c) {
  return __builtin_amdgcn_mfma_f32_16x16x32_bf16(a, b, c, 0, 0, 0);
}

// XOR-swizzled LDS addressing: tiles are [rows][64 u16], 16B chunk index XORed
// with (row & 7). Keeps every b128 access 16B-aligned AND bank-conflict-free
// for both row-fragment reads and column-ish scatter writes (LD=64 dword
// stride 32 would otherwise alias ALL rows onto the same banks).
__device__ __forceinline__ int sw(int r, int c) {      // element (u16) address
  return (r << 6) + ((((c >> 3) ^ r) & 7) << 3) + (c & 7);
}
__device__ __forceinline__ int swc(int r, int ch) {    // chunk (16B) address
  return (r << 6) + (((ch ^ r) & 7) << 3);
}

// Prep: build bf16 weight image in ws (pre-swizzled, rows of 64 u16):
//   rows 0-47:  M_t[c'][c] = scale * sum_h Wq[c][h]*Wk[c'][h]   ((scale*Wq@Wk^T)^T)
//   rows 48-95: Wv_t[h][c] = Wv[c][h]
// cols 48-63 zeroed (K-dim pad; also serves as QM pad in head_main's overlay).
// Weights staged to LDS first: the round-1 version did ~1300 scalar global
// loads/thread from one block = ~245 us latency-bound. LDS staging -> ~4 us.
__global__ __launch_bounds__(256) void head_prep(const float* __restrict__ Wq,
                                                 const float* __restrict__ Wk,
                                                 const float* __restrict__ Wv,
                                                 u16* __restrict__ ws) {
  __shared__ float wq[2304], wk[2304], wv[2304];
  const float scale = 0.14433756729740643f;  // 1/sqrt(48)
  for (int i = threadIdx.x; i < 2304; i += 256) {
    wq[i] = Wq[i];
    wk[i] = Wk[i];
    wv[i] = Wv[i];
  }
  __syncthreads();
  for (int idx = threadIdx.x; idx < 96 * 64; idx += 256) {
    int r = idx >> 6, c = idx & 63;
    float v = 0.f;
    if (c < 48) {
      if (r < 48) {
        float a = 0.f;
        for (int h = 0; h < 48; ++h) a += wq[c * 48 + h] * wk[r * 48 + h];
        v = a * scale;
      } else {
        v = wv[c * 48 + (r - 48)];
      }
    }
    ws[sw(r, c)] = f2b(v);
  }
}

// One workgroup (4 waves) per batch element. Wave w owns t-rows [16w,16w+16).
// qm = x@M ; S = qm@x^T (== scale*q@k^T) ; P = softmax_causal(S) ; out = P@(x@Wv)
// LDS regions (26624 B -> 6 blocks/CU, 24 waves = 75% occupancy cap):
//   R0: 96 rows = W_M(0-47) | W_V(48-95); after proj barrier overlaid by QM(0-63)
//       (QM K-pad chunks 6,7 inherited as zeros from the weight image)
//   X : 64 rows; after S barrier overlaid by P
//   VT: 48 rows (V transposed, h-major / s-inner)
__global__ __launch_bounds__(256, 6) void head_main(const float* __restrict__ x,
                                                    const u16* __restrict__ wimg,
                                                    float* __restrict__ out) {
  __shared__ u16 lds[208 * 64];
  u16* const R0 = lds;
  u16* const X  = lds + 96 * 64;
  u16* const VT = lds + 160 * 64;

  const int tid  = threadIdx.x;
  const int lane = tid & 63;
  const int w    = tid >> 6;
  const int qd   = lane >> 4;
  const int col  = lane & 15;
  const long b   = blockIdx.x;

  // ---- stage weight image (already bf16 + swizzled + padded): 768 uint4 ----
  {
    const uint4* src = (const uint4*)wimg;
    uint4* dst = (uint4*)lds;
    dst[tid]       = src[tid];
    dst[tid + 256] = src[tid + 256];
    dst[tid + 512] = src[tid + 512];
  }
  // ---- stage x -> bf16 LDS (coalesced float4 global reads) ----
  {
    const float* xb = x + b * 3072;
#pragma unroll
    for (int it = 0; it < 3; ++it) {
      int flat = tid * 4 + it * 1024;  // fully coalesced
      float4 v = *(const float4*)(xb + flat);
      int row = flat / 48;
      int c0  = flat % 48;             // multiple of 4 -> stays inside one chunk
      ushort4 pk;
      pk.x = f2b(v.x); pk.y = f2b(v.y); pk.z = f2b(v.z); pk.w = f2b(v.w);
      *(ushort4*)(X + sw(row, c0)) = pk;
    }
    // zero X K-pad (chunks 6,7 of all 64 rows): 256 ushort4, one per thread
    int zr = tid >> 2;
    int zq = tid & 3;
    ushort4 z = {0, 0, 0, 0};
    *(ushort4*)(X + swc(zr, 6 + (zq >> 1)) + (zq & 1) * 4) = z;
  }
  __syncthreads();

  // ---- projections: V = x@Wv -> VT (transposed now), QM = x@M -> regs ----
  f32x4 aq[3];
  {
    const int ar = 16 * w + col;
    const bf16x8 xa0 = *(const bf16x8*)(X + swc(ar, qd));
    const bf16x8 xa1 = *(const bf16x8*)(X + swc(ar, qd + 4));
    const u16* WM = R0;
    const u16* WV = R0 + 48 * 64;
#pragma unroll
    for (int n = 0; n < 3; ++n) {
      const int br = 16 * n + col;
      const int b0 = swc(br, qd);
      const int b1 = swc(br, qd + 4);
      f32x4 av = {0.f, 0.f, 0.f, 0.f};
      av = mfma16(xa0, *(const bf16x8*)(WV + b0), av);
      av = mfma16(xa1, *(const bf16x8*)(WV + b1), av);
      f32x4 a = {0.f, 0.f, 0.f, 0.f};
      a = mfma16(xa0, *(const bf16x8*)(WM + b0), a);
      a = mfma16(xa1, *(const bf16x8*)(WM + b1), a);
      aq[n] = a;
      // V tile D[s_loc][h_loc] -> VT[h][s], 4 consecutive s -> one ushort4
      ushort4 pv;
      pv.x = f2b(av[0]); pv.y = f2b(av[1]); pv.z = f2b(av[2]); pv.w = f2b(av[3]);
      *(ushort4*)(VT + sw(16 * n + col, 16 * w + qd * 4)) = pv;
    }
  }
  __syncthreads();  // all reads of W (R0) and X done; R0 becomes QM

  // ---- QM overlay write (own 16 rows) ----
#pragma unroll
  for (int n = 0; n < 3; ++n)
#pragma unroll
    for (int i = 0; i < 4; ++i)
      R0[sw(16 * w + qd * 4 + i, 16 * n + col)] = f2b(aq[n][i]);
  __threadfence_block();  // same-wave write->read ordering (no barrier needed)

  // ---- S = QM @ X^T : A from own QM rows, B from X rows ----
  float sv[4][4];
  {
    const int ar = 16 * w + col;
    const bf16x8 qa0 = *(const bf16x8*)(R0 + swc(ar, qd));
    const bf16x8 qa1 = *(const bf16x8*)(R0 + swc(ar, qd + 4));
#pragma unroll
    for (int st = 0; st < 4; ++st) {
      const int br = 16 * st + col;
      f32x4 a = {0.f, 0.f, 0.f, 0.f};
      a = mfma16(qa0, *(const bf16x8*)(X + swc(br, qd)), a);
      a = mfma16(qa1, *(const bf16x8*)(X + swc(br, qd + 4)), a);
#pragma unroll
      for (int i = 0; i < 4; ++i) sv[st][i] = a[i];
    }
  }

  // ---- causal mask + softmax (rows fit in regs; 16-lane butterflies) ----
  float m4[4] = {-INFINITY, -INFINITY, -INFINITY, -INFINITY};
#pragma unroll
  for (int st = 0; st < 4; ++st)
#pragma unroll
    for (int i = 0; i < 4; ++i) {
      int tg = 16 * w + qd * 4 + i;
      int sg = 16 * st + col;
      float v = (sg <= tg) ? sv[st][i] : -INFINITY;
      sv[st][i] = v;
      m4[i] = fmaxf(m4[i], v);
    }
#pragma unroll
  for (int d = 1; d < 16; d <<= 1)
#pragma unroll
    for (int i = 0; i < 4; ++i) m4[i] = fmaxf(m4[i], __shfl_xor(m4[i], d, 64));
  float l4[4] = {0.f, 0.f, 0.f, 0.f};
#pragma unroll
  for (int st = 0; st < 4; ++st)
#pragma unroll
    for (int i = 0; i < 4; ++i) {
      float p = __expf(sv[st][i] - m4[i]);  // exp(-inf)=0 handles the mask
      sv[st][i] = p;
      l4[i] += p;
    }
#pragma unroll
  for (int d = 1; d < 16; d <<= 1)
#pragma unroll
    for (int i = 0; i < 4; ++i) l4[i] += __shfl_xor(l4[i], d, 64);

  __syncthreads();  // all waves' S-phase X reads done; X becomes P

  // ---- write P' (unnormalized) over X (own 16 rows) ----
#pragma unroll
  for (int st = 0; st < 4; ++st)
#pragma unroll
    for (int i = 0; i < 4; ++i)
      X[sw(16 * w + qd * 4 + i, 16 * st + col)] = f2b(sv[st][i]);
  __threadfence_block();  // same-wave write->read ordering

  // ---- O = P' @ V (A from own P rows, B from VT), scale rows by 1/l ----
  f32x4 o0 = {0.f, 0.f, 0.f, 0.f}, o1 = o0, o2 = o0;
  {
    const int pr = 16 * w + col;
#pragma unroll
    for (int kt = 0; kt < 2; ++kt) {
      const int ch = qd + 4 * kt;
      bf16x8 pa = *(const bf16x8*)(X + swc(pr, ch));
      o0 = mfma16(pa, *(const bf16x8*)(VT + swc(0  + col, ch)), o0);
      o1 = mfma16(pa, *(const bf16x8*)(VT + swc(16 + col, ch)), o1);
      o2 = mfma16(pa, *(const bf16x8*)(VT + swc(32 + col, ch)), o2);
    }
  }
  float rl[4];
#pragma unroll
  for (int i = 0; i < 4; ++i) rl[i] = __builtin_amdgcn_rcpf(l4[i]);

  float* ob = out + b * 3072 + (16 * w + qd * 4) * 48 + col;
#pragma unroll
  for (int i = 0; i < 4; ++i) {  // per-quad 64B segments -> fine coalescing
    ob[i * 48 +  0] = o0[i] * rl[i];
    ob[i * 48 + 16] = o1[i] * rl[i];
    ob[i * 48 + 32] = o2[i] * rl[i];
  }
}

extern "C" void kernel_launch(void* const* d_in, const int* in_sizes, int n_in,
                              void* d_out, int out_size, void* d_ws, size_t ws_size,
                              hipStream_t stream) {
  const float* x  = (const float*)d_in[0];
  const float* Wq = (const float*)d_in[1];
  const float* Wk = (const float*)d_in[2];
  const float* Wv = (const float*)d_in[3];
  u16* wimg = (u16*)d_ws;  // 96*64 u16 = 12288 B
  head_prep<<<1, 256, 0, stream>>>(Wq, Wk, Wv, wimg);
  head_main<<<16384, 256, 0, stream>>>(x, wimg, (float*)d_out);
}